// Round 4
// baseline (2632.189 us; speedup 1.0000x reference)
//
#include <hip/hip_runtime.h>

// Inputs: fp32. Outputs: fp32 (established round 3: PASSED).

constexpr int BB = 4;
constexpr int NN = 4096;
constexpr int M1 = 2048;
constexpr int M2 = 512;

// Exact fp32 squared distance matching numpy's (dx*dx) + (dy*dy), no fma contraction.
__device__ __forceinline__ float d2_exact(float dx, float dy) {
    return __fadd_rn(__fmul_rn(dx, dx), __fmul_rn(dy, dy));
}

__device__ __forceinline__ unsigned long long shflx64(unsigned long long v, int off) {
    unsigned lo = (unsigned)v, hi = (unsigned)(v >> 32);
    lo = __shfl_xor(lo, off, 64);
    hi = __shfl_xor(hi, off, 64);
    return ((unsigned long long)hi << 32) | (unsigned long long)lo;
}

// pick the slot with the larger (key_hi,key_lo) — keys are unique (contain ~j).
__device__ __forceinline__ uint4 u4max(uint4 a, uint4 b) {
    unsigned long long ka = ((unsigned long long)a.x << 32) | (unsigned long long)a.y;
    unsigned long long kb = ((unsigned long long)b.x << 32) | (unsigned long long)b.y;
    return kb > ka ? b : a;
}

// ---------------------------------------------------------------------------
// lf = tanh(tanh(x@W1+b1)@W2+b2) -> out (fp32); also
// y1[j,f] = lf_j@c1W[0:64] + zones_j*c1W[64] + pos_j@c1W[65:67] + c1b (fp32 ws)
// ---------------------------------------------------------------------------
__global__ __launch_bounds__(256) void k_lf_y1(
    const float2* __restrict__ x, const float* __restrict__ zones,
    const float* __restrict__ W1, const float* __restrict__ b1,
    const float* __restrict__ W2, const float* __restrict__ b2,
    const float* __restrict__ c1W, const float* __restrict__ c1b,
    float* __restrict__ out_lf, float* __restrict__ y1)
{
    __shared__ float sh[4][64];
    __shared__ float sl[4][64];
    int tid = threadIdx.x;
    int p = tid >> 6, f = tid & 63;
    size_t pt = (size_t)blockIdx.x * 4 + p;      // 0 .. BB*NN-1
    float2 xv = x[pt];
    float hid = tanhf(xv.x * W1[f] + xv.y * W1[64 + f] + b1[f]);
    sh[p][f] = hid;
    __syncthreads();
    float acc = b2[f];
#pragma unroll
    for (int c = 0; c < 64; ++c) acc += sh[p][c] * W2[c * 64 + f];
    float lf = tanhf(acc);
    sl[p][f] = lf;
    out_lf[pt * 64 + f] = lf;
    __syncthreads();
    float acc2 = c1b[f] + zones[pt] * c1W[64 * 64 + f]
               + xv.x * c1W[65 * 64 + f] + xv.y * c1W[66 * 64 + f];
#pragma unroll
    for (int c = 0; c < 64; ++c) acc2 += sl[p][c] * c1W[c * 64 + f];
    y1[pt * 64 + f] = acc2;
}

// ---------------------------------------------------------------------------
// Farthest point sampling — latency-optimized, bit-exact vs reference scan:
//   min_d2 init 1e10; min-update vs last center; argmax with FIRST-index
//   tie-break (u64 key = bits(min_d2)<<32 | (0xFFFFFFFF - j), max-reduce).
// Points live in registers (PPT per lane). Per-lane argmax via strict-> float
// compare (keeps smallest j within a lane: j ascends with q). The 64-lane
// butterfly carries the winner's (x,y) payload so no dependent position fetch
// is needed. Parity-double-buffered wave slots -> ONE barrier per iteration.
// ---------------------------------------------------------------------------
template<int NP, int M>
__global__ __launch_bounds__(512) void k_fps(const float2* __restrict__ pos,
                                             float* __restrict__ ctr)
{
    constexpr int PPT = NP / 512;
    __shared__ uint4 slots[2][8];
    int b = blockIdx.x, tid = threadIdx.x;
    const float2* p = pos + (size_t)b * NP;

    float px[PPT], py[PPT], md[PPT];
    unsigned lowk[PPT];
#pragma unroll
    for (int q = 0; q < PPT; ++q) {
        int j = tid + q * 512;
        float2 v = p[j];
        px[q] = v.x; py[q] = v.y;
        md[q] = 1e10f;
        lowk[q] = 0xFFFFFFFFu - (unsigned)j;
    }
    float2 c0 = p[0];
    float cx = c0.x, cy = c0.y;
    float* co = ctr + (size_t)b * M * 2;
    if (tid == 0) { co[0] = cx; co[1] = cy; }
    int wid = tid >> 6;

    for (int it = 1; it < M; ++it) {
        // per-lane update + argmax (branchless cndmask tracking)
        float bm = -1.0f, bx = 0.0f, by = 0.0f;
        unsigned bl = 0u;
#pragma unroll
        for (int q = 0; q < PPT; ++q) {
            float dx = px[q] - cx, dy = py[q] - cy;
            float m = fminf(md[q], d2_exact(dx, dy));
            md[q] = m;
            bool g = m > bm;                 // strict: first index wins ties
            bm = g ? m : bm;
            bl = g ? lowk[q] : bl;
            bx = g ? px[q] : bx;
            by = g ? py[q] : by;
        }
        // exact u64 key, built once; payload-carrying 64-lane butterfly
        unsigned long long k =
            ((unsigned long long)__float_as_uint(bm) << 32) | (unsigned long long)bl;
#pragma unroll
        for (int off = 1; off < 64; off <<= 1) {
            unsigned long long ok = shflx64(k, off);
            float ox = __shfl_xor(bx, off, 64);
            float oy = __shfl_xor(by, off, 64);
            bool t = ok > k;                 // keys unique -> no tie here
            k = t ? ok : k;
            bx = t ? ox : bx;
            by = t ? oy : by;
        }
        int par = it & 1;
        if ((tid & 63) == 0)
            slots[par][wid] = make_uint4((unsigned)(k >> 32), (unsigned)k,
                                         __float_as_uint(bx), __float_as_uint(by));
        __syncthreads();                     // the only barrier per iteration
        uint4 s0 = slots[par][0], s1 = slots[par][1];
        uint4 s2 = slots[par][2], s3 = slots[par][3];
        uint4 s4 = slots[par][4], s5 = slots[par][5];
        uint4 s6 = slots[par][6], s7 = slots[par][7];
        uint4 w = u4max(u4max(u4max(s0, s1), u4max(s2, s3)),
                        u4max(u4max(s4, s5), u4max(s6, s7)));
        cx = __uint_as_float(w.z);
        cy = __uint_as_float(w.w);
        if (tid == 0) { co[2 * it] = cx; co[2 * it + 1] = cy; }
    }
}

// ---------------------------------------------------------------------------
// Set abstraction: h[i,f] = max_{j: d2(j,i)<=r2} y[j,f]  -  ctr_i @ W_rel.
// One block per center. Exact ball membership; max is order-free.
// ---------------------------------------------------------------------------
__global__ __launch_bounds__(256) void k_sa(
    const float2* __restrict__ candpos, const float* __restrict__ y,
    const float* __restrict__ ctr, const float* __restrict__ W,
    int NP, int F, int relrow, float r2, float* __restrict__ hout)
{
    __shared__ int cnt;
    __shared__ int list[4096];
    int tid = threadIdx.x;
    int b = blockIdx.y;
    size_t crow = (size_t)b * gridDim.x + blockIdx.x;
    if (tid == 0) cnt = 0;
    __syncthreads();
    float cx = ctr[crow * 2], cy = ctr[crow * 2 + 1];
    const float2* cp = candpos + (size_t)b * NP;
    for (int j = tid; j < NP; j += 256) {
        float2 pj = cp[j];
        float d2 = d2_exact(pj.x - cx, pj.y - cy);
        if (d2 <= r2) { int t = atomicAdd(&cnt, 1); list[t] = j; }
    }
    __syncthreads();
    int n = cnt;
    for (int f = tid; f < F; f += 256) {
        float m = -3.0e38f;
        for (int t = 0; t < n; ++t)
            m = fmaxf(m, y[((size_t)b * NP + list[t]) * F + f]);
        float ct = cx * W[(size_t)relrow * F + f] + cy * W[(size_t)(relrow + 1) * F + f];
        hout[crow * F + f] = m - ct;
    }
}

// ---------------------------------------------------------------------------
// y2[j,f] = h1_j @ c2W[0:64] + pos_j @ c2W[64:66] + c2b   (one block / point)
// ---------------------------------------------------------------------------
__global__ __launch_bounds__(128) void k_y2(
    const float* __restrict__ h1, const float* __restrict__ p1,
    const float* __restrict__ W, const float* __restrict__ bb,
    float* __restrict__ y2)
{
    __shared__ float sh[64];
    size_t row = blockIdx.x;
    int f = threadIdx.x;
    if (f < 64) sh[f] = h1[row * 64 + f];
    __syncthreads();
    float acc = bb[f] + p1[row * 2] * W[64 * 128 + f]
              + p1[row * 2 + 1] * W[65 * 128 + f];
#pragma unroll
    for (int c = 0; c < 64; ++c) acc += sh[c] * W[c * 128 + f];
    y2[row * 128 + f] = acc;
}

// ---------------------------------------------------------------------------
// g[i,f] = [h2_i, pos_i] @ c3W + c3b; partial max over 8 rows/thread.
// ---------------------------------------------------------------------------
__global__ __launch_bounds__(256) void k_g(
    const float* __restrict__ h2, const float* __restrict__ p2,
    const float* __restrict__ W3, const float* __restrict__ b3,
    float* __restrict__ part)
{
    int f = blockIdx.x * 256 + threadIdx.x;
    int b = blockIdx.z;
    int i0 = blockIdx.y * 8;
    float acc[8];
    float bbv = b3[f];
#pragma unroll
    for (int ii = 0; ii < 8; ++ii) acc[ii] = bbv;
    const float* hrow = h2 + ((size_t)b * M2 + i0) * 128;
    for (int c = 0; c < 128; ++c) {
        float w = W3[(size_t)c * 1024 + f];
#pragma unroll
        for (int ii = 0; ii < 8; ++ii) acc[ii] += hrow[ii * 128 + c] * w;
    }
    float wx = W3[(size_t)128 * 1024 + f];
    float wy = W3[(size_t)129 * 1024 + f];
    const float* prow = p2 + ((size_t)b * M2 + i0) * 2;
    float m = -3.0e38f;
#pragma unroll
    for (int ii = 0; ii < 8; ++ii) {
        float g = acc[ii] + prow[ii * 2] * wx + prow[ii * 2 + 1] * wy;
        m = fmaxf(m, g);
    }
    part[((size_t)b * 64 + blockIdx.y) * 1024 + f] = m;
}

__global__ __launch_bounds__(256) void k_gmax(const float* __restrict__ part,
                                              float* __restrict__ outg)
{
    int f = blockIdx.x * 256 + threadIdx.x;   // 0..4095
    int b = f >> 10, fl = f & 1023;
    float m = -3.0e38f;
#pragma unroll 8
    for (int ig = 0; ig < 64; ++ig)
        m = fmaxf(m, part[((size_t)b * 64 + ig) * 1024 + fl]);
    outg[f] = m;
}

extern "C" void kernel_launch(void* const* d_in, const int* in_sizes, int n_in,
                              void* d_out, int out_size, void* d_ws, size_t ws_size,
                              hipStream_t stream)
{
    const float* x    = (const float*)d_in[0];
    const float* zon  = (const float*)d_in[1];
    const float* lfW1 = (const float*)d_in[2];
    const float* lfb1 = (const float*)d_in[3];
    const float* lfW2 = (const float*)d_in[4];
    const float* lfb2 = (const float*)d_in[5];
    const float* c1W  = (const float*)d_in[6];
    const float* c1b  = (const float*)d_in[7];
    const float* c2W  = (const float*)d_in[8];
    const float* c2b  = (const float*)d_in[9];
    const float* c3W  = (const float*)d_in[10];
    const float* c3b  = (const float*)d_in[11];
    float* out = (float*)d_out;

    // Workspace (fp32). "big" (4 MB) reused: y1 -> y2 -> part.
    char* w = (char*)d_ws;
    float* big = (float*)w;                    w += (size_t)BB * NN * 64 * 4;   // 4 MB
    float* p1  = (float*)w;                    w += (size_t)BB * M1 * 2 * 4;
    float* h1  = (float*)w;                    w += (size_t)BB * M1 * 64 * 4;   // 2 MB
    float* p2  = (float*)w;                    w += (size_t)BB * M2 * 2 * 4;
    float* h2  = (float*)w;                    w += (size_t)BB * M2 * 128 * 4;  // 1 MB
    float* y1 = big, * y2 = big, * part = big;

    k_lf_y1<<<BB * NN / 4, 256, 0, stream>>>((const float2*)x, zon, lfW1, lfb1,
                                             lfW2, lfb2, c1W, c1b, out, y1);
    k_fps<NN, M1><<<BB, 512, 0, stream>>>((const float2*)x, p1);
    k_sa<<<dim3(M1, BB), 256, 0, stream>>>((const float2*)x, y1, p1, c1W,
                                           NN, 64, 65, 0.25f, h1);
    k_fps<M1, M2><<<BB, 512, 0, stream>>>((const float2*)p1, p2);
    k_y2<<<BB * M1, 128, 0, stream>>>(h1, p1, c2W, c2b, y2);
    k_sa<<<dim3(M2, BB), 256, 0, stream>>>((const float2*)p1, y2, p2, c2W,
                                           M1, 128, 64, 1.0f, h2);
    k_g<<<dim3(4, 64, BB), 256, 0, stream>>>(h2, p2, c3W, c3b, part);
    k_gmax<<<16, 256, 0, stream>>>(part, out + (size_t)BB * NN * 64);
}

// Round 5
// 2056.352 us; speedup vs baseline: 1.2800x; 1.2800x over previous
//
#include <hip/hip_runtime.h>

// Inputs: fp32. Outputs: fp32 (established round 3: PASSED).

constexpr int BB = 4;
constexpr int NN = 4096;
constexpr int M1 = 2048;
constexpr int M2 = 512;

// Exact fp32 squared distance matching numpy's (dx*dx) + (dy*dy), no fma contraction.
__device__ __forceinline__ float d2_exact(float dx, float dy) {
    return __fadd_rn(__fmul_rn(dx, dx), __fmul_rn(dy, dy));
}

// pick the slot with the larger (key_hi,key_lo) — keys unique (contain ~j).
__device__ __forceinline__ uint4 u4max(uint4 a, uint4 b) {
    unsigned long long ka = ((unsigned long long)a.x << 32) | (unsigned long long)a.y;
    unsigned long long kb = ((unsigned long long)b.x << 32) | (unsigned long long)b.y;
    return kb > ka ? b : a;
}

// One DPP combine stage: pull (key,payload) from CTRL-selected lanes, keep max.
// old = own value => lanes with invalid DPP source keep themselves (idempotent
// under max). v_mov_b32_dpp is VALU-speed (~2-4 cyc) vs ~50 cyc for ds_permute
// shuffles (measured R3->R4 delta).
template<int CTRL>
__device__ __forceinline__ void dppc(unsigned& hi, unsigned& lo, float& x, float& y) {
    unsigned ohi = (unsigned)__builtin_amdgcn_update_dpp((int)hi, (int)hi, CTRL, 0xF, 0xF, false);
    unsigned olo = (unsigned)__builtin_amdgcn_update_dpp((int)lo, (int)lo, CTRL, 0xF, 0xF, false);
    float ox = __int_as_float(__builtin_amdgcn_update_dpp(__float_as_int(x), __float_as_int(x), CTRL, 0xF, 0xF, false));
    float oy = __int_as_float(__builtin_amdgcn_update_dpp(__float_as_int(y), __float_as_int(y), CTRL, 0xF, 0xF, false));
    unsigned long long ko = ((unsigned long long)ohi << 32) | (unsigned long long)olo;
    unsigned long long kk = ((unsigned long long)hi  << 32) | (unsigned long long)lo;
    bool t = ko > kk;
    hi = t ? ohi : hi;  lo = t ? olo : lo;
    x  = t ? ox  : x;   y  = t ? oy  : y;
}

// ---------------------------------------------------------------------------
// lf = tanh(tanh(x@W1+b1)@W2+b2) -> out (fp32); also
// y1[j,f] = lf_j@c1W[0:64] + zones_j*c1W[64] + pos_j@c1W[65:67] + c1b (fp32 ws)
// ---------------------------------------------------------------------------
__global__ __launch_bounds__(256) void k_lf_y1(
    const float2* __restrict__ x, const float* __restrict__ zones,
    const float* __restrict__ W1, const float* __restrict__ b1,
    const float* __restrict__ W2, const float* __restrict__ b2,
    const float* __restrict__ c1W, const float* __restrict__ c1b,
    float* __restrict__ out_lf, float* __restrict__ y1)
{
    __shared__ float sh[4][64];
    __shared__ float sl[4][64];
    int tid = threadIdx.x;
    int p = tid >> 6, f = tid & 63;
    size_t pt = (size_t)blockIdx.x * 4 + p;      // 0 .. BB*NN-1
    float2 xv = x[pt];
    float hid = tanhf(xv.x * W1[f] + xv.y * W1[64 + f] + b1[f]);
    sh[p][f] = hid;
    __syncthreads();
    float acc = b2[f];
#pragma unroll
    for (int c = 0; c < 64; ++c) acc += sh[p][c] * W2[c * 64 + f];
    float lf = tanhf(acc);
    sl[p][f] = lf;
    out_lf[pt * 64 + f] = lf;
    __syncthreads();
    float acc2 = c1b[f] + zones[pt] * c1W[64 * 64 + f]
               + xv.x * c1W[65 * 64 + f] + xv.y * c1W[66 * 64 + f];
#pragma unroll
    for (int c = 0; c < 64; ++c) acc2 += sl[p][c] * c1W[c * 64 + f];
    y1[pt * 64 + f] = acc2;
}

// ---------------------------------------------------------------------------
// Farthest point sampling — DPP-reduced, bit-exact vs reference scan:
//   min_d2 init 1e10; min vs last center; argmax with FIRST-index tie-break
//   (u64 key = bits(min_d2)<<32 | (0xFFFFFFFF - j), max-reduce; md>=0 so the
//   f32 bit pattern is value-monotone).
// 256 threads (4 waves, 1/SIMD). Points in registers (PPT/lane). Per-lane
// argmax via strict-> (q ascends with j => first index wins). Wave reduce via
// 6 DPP stages carrying (key, x, y); lane 63 writes its wave slot; parity
// double-buffer => ONE barrier/iter; 4-slot tree after.
// ---------------------------------------------------------------------------
template<int NP, int M>
__global__ __launch_bounds__(256) void k_fps(const float2* __restrict__ pos,
                                             float* __restrict__ ctr)
{
    constexpr int PPT = NP / 256;
    __shared__ uint4 slots[2][4];
    int b = blockIdx.x, tid = threadIdx.x;
    const float2* p = pos + (size_t)b * NP;

    float px[PPT], py[PPT], md[PPT];
#pragma unroll
    for (int q = 0; q < PPT; ++q) {
        float2 v = p[tid + q * 256];
        px[q] = v.x; py[q] = v.y;
        md[q] = 1e10f;
    }
    float2 c0 = p[0];
    float cx = c0.x, cy = c0.y;
    float* co = ctr + (size_t)b * M * 2;
    if (tid == 0) { co[0] = cx; co[1] = cy; }

    for (int it = 1; it < M; ++it) {
        // per-lane min-update + argmax (branchless)
        float bm = -1.0f, bx = 0.0f, by = 0.0f;
        int bq = 0;
#pragma unroll
        for (int q = 0; q < PPT; ++q) {
            float dx = px[q] - cx, dy = py[q] - cy;
            float m = fminf(md[q], d2_exact(dx, dy));
            md[q] = m;
            bool g = m > bm;                 // strict: first index wins ties
            bm = g ? m : bm;
            bq = g ? q : bq;
            bx = g ? px[q] : bx;
            by = g ? py[q] : by;
        }
        unsigned hi = __float_as_uint(bm);
        unsigned lo = 0xFFFFFFFFu - (unsigned)(tid + (bq << 8));   // ~j
        // wave max via DPP ladder -> lane 63
        dppc<0x111>(hi, lo, bx, by);   // row_shr:1
        dppc<0x112>(hi, lo, bx, by);   // row_shr:2
        dppc<0x114>(hi, lo, bx, by);   // row_shr:4
        dppc<0x118>(hi, lo, bx, by);   // row_shr:8
        dppc<0x142>(hi, lo, bx, by);   // row_bcast:15
        dppc<0x143>(hi, lo, bx, by);   // row_bcast:31
        int par = it & 1;
        if ((tid & 63) == 63)
            slots[par][tid >> 6] = make_uint4(hi, lo, __float_as_uint(bx),
                                              __float_as_uint(by));
        __syncthreads();                 // the only barrier per iteration
        uint4 s0 = slots[par][0], s1 = slots[par][1];
        uint4 s2 = slots[par][2], s3 = slots[par][3];
        uint4 w = u4max(u4max(s0, s1), u4max(s2, s3));
        cx = __uint_as_float(w.z);
        cy = __uint_as_float(w.w);
        if (tid == 0) { co[2 * it] = cx; co[2 * it + 1] = cy; }
    }
}

// ---------------------------------------------------------------------------
// Set abstraction: h[i,f] = max_{j: d2(j,i)<=r2} y[j,f]  -  ctr_i @ W_rel.
// One block per center. Exact ball membership; max is order-free.
// ---------------------------------------------------------------------------
__global__ __launch_bounds__(256) void k_sa(
    const float2* __restrict__ candpos, const float* __restrict__ y,
    const float* __restrict__ ctr, const float* __restrict__ W,
    int NP, int F, int relrow, float r2, float* __restrict__ hout)
{
    __shared__ int cnt;
    __shared__ int list[4096];
    int tid = threadIdx.x;
    int b = blockIdx.y;
    size_t crow = (size_t)b * gridDim.x + blockIdx.x;
    if (tid == 0) cnt = 0;
    __syncthreads();
    float cx = ctr[crow * 2], cy = ctr[crow * 2 + 1];
    const float2* cp = candpos + (size_t)b * NP;
    for (int j = tid; j < NP; j += 256) {
        float2 pj = cp[j];
        float d2 = d2_exact(pj.x - cx, pj.y - cy);
        if (d2 <= r2) { int t = atomicAdd(&cnt, 1); list[t] = j; }
    }
    __syncthreads();
    int n = cnt;
    for (int f = tid; f < F; f += 256) {
        float m = -3.0e38f;
        for (int t = 0; t < n; ++t)
            m = fmaxf(m, y[((size_t)b * NP + list[t]) * F + f]);
        float ct = cx * W[(size_t)relrow * F + f] + cy * W[(size_t)(relrow + 1) * F + f];
        hout[crow * F + f] = m - ct;
    }
}

// ---------------------------------------------------------------------------
// y2[j,f] = h1_j @ c2W[0:64] + pos_j @ c2W[64:66] + c2b   (one block / point)
// ---------------------------------------------------------------------------
__global__ __launch_bounds__(128) void k_y2(
    const float* __restrict__ h1, const float* __restrict__ p1,
    const float* __restrict__ W, const float* __restrict__ bb,
    float* __restrict__ y2)
{
    __shared__ float sh[64];
    size_t row = blockIdx.x;
    int f = threadIdx.x;
    if (f < 64) sh[f] = h1[row * 64 + f];
    __syncthreads();
    float acc = bb[f] + p1[row * 2] * W[64 * 128 + f]
              + p1[row * 2 + 1] * W[65 * 128 + f];
#pragma unroll
    for (int c = 0; c < 64; ++c) acc += sh[c] * W[c * 128 + f];
    y2[row * 128 + f] = acc;
}

// ---------------------------------------------------------------------------
// g[i,f] = [h2_i, pos_i] @ c3W + c3b; partial max over 8 rows/thread.
// ---------------------------------------------------------------------------
__global__ __launch_bounds__(256) void k_g(
    const float* __restrict__ h2, const float* __restrict__ p2,
    const float* __restrict__ W3, const float* __restrict__ b3,
    float* __restrict__ part)
{
    int f = blockIdx.x * 256 + threadIdx.x;
    int b = blockIdx.z;
    int i0 = blockIdx.y * 8;
    float acc[8];
    float bbv = b3[f];
#pragma unroll
    for (int ii = 0; ii < 8; ++ii) acc[ii] = bbv;
    const float* hrow = h2 + ((size_t)b * M2 + i0) * 128;
    for (int c = 0; c < 128; ++c) {
        float w = W3[(size_t)c * 1024 + f];
#pragma unroll
        for (int ii = 0; ii < 8; ++ii) acc[ii] += hrow[ii * 128 + c] * w;
    }
    float wx = W3[(size_t)128 * 1024 + f];
    float wy = W3[(size_t)129 * 1024 + f];
    const float* prow = p2 + ((size_t)b * M2 + i0) * 2;
    float m = -3.0e38f;
#pragma unroll
    for (int ii = 0; ii < 8; ++ii) {
        float g = acc[ii] + prow[ii * 2] * wx + prow[ii * 2 + 1] * wy;
        m = fmaxf(m, g);
    }
    part[((size_t)b * 64 + blockIdx.y) * 1024 + f] = m;
}

__global__ __launch_bounds__(256) void k_gmax(const float* __restrict__ part,
                                              float* __restrict__ outg)
{
    int f = blockIdx.x * 256 + threadIdx.x;   // 0..4095
    int b = f >> 10, fl = f & 1023;
    float m = -3.0e38f;
#pragma unroll 8
    for (int ig = 0; ig < 64; ++ig)
        m = fmaxf(m, part[((size_t)b * 64 + ig) * 1024 + fl]);
    outg[f] = m;
}

extern "C" void kernel_launch(void* const* d_in, const int* in_sizes, int n_in,
                              void* d_out, int out_size, void* d_ws, size_t ws_size,
                              hipStream_t stream)
{
    const float* x    = (const float*)d_in[0];
    const float* zon  = (const float*)d_in[1];
    const float* lfW1 = (const float*)d_in[2];
    const float* lfb1 = (const float*)d_in[3];
    const float* lfW2 = (const float*)d_in[4];
    const float* lfb2 = (const float*)d_in[5];
    const float* c1W  = (const float*)d_in[6];
    const float* c1b  = (const float*)d_in[7];
    const float* c2W  = (const float*)d_in[8];
    const float* c2b  = (const float*)d_in[9];
    const float* c3W  = (const float*)d_in[10];
    const float* c3b  = (const float*)d_in[11];
    float* out = (float*)d_out;

    // Workspace (fp32). "big" (4 MB) reused: y1 -> y2 -> part.
    char* w = (char*)d_ws;
    float* big = (float*)w;                    w += (size_t)BB * NN * 64 * 4;   // 4 MB
    float* p1  = (float*)w;                    w += (size_t)BB * M1 * 2 * 4;
    float* h1  = (float*)w;                    w += (size_t)BB * M1 * 64 * 4;   // 2 MB
    float* p2  = (float*)w;                    w += (size_t)BB * M2 * 2 * 4;
    float* h2  = (float*)w;                    w += (size_t)BB * M2 * 128 * 4;  // 1 MB
    float* y1 = big, * y2 = big, * part = big;

    k_lf_y1<<<BB * NN / 4, 256, 0, stream>>>((const float2*)x, zon, lfW1, lfb1,
                                             lfW2, lfb2, c1W, c1b, out, y1);
    k_fps<NN, M1><<<BB, 256, 0, stream>>>((const float2*)x, p1);
    k_sa<<<dim3(M1, BB), 256, 0, stream>>>((const float2*)x, y1, p1, c1W,
                                           NN, 64, 65, 0.25f, h1);
    k_fps<M1, M2><<<BB, 256, 0, stream>>>((const float2*)p1, p2);
    k_y2<<<BB * M1, 128, 0, stream>>>(h1, p1, c2W, c2b, y2);
    k_sa<<<dim3(M2, BB), 256, 0, stream>>>((const float2*)p1, y2, p2, c2W,
                                           M1, 128, 64, 1.0f, h2);
    k_g<<<dim3(4, 64, BB), 256, 0, stream>>>(h2, p2, c3W, c3b, part);
    k_gmax<<<16, 256, 0, stream>>>(part, out + (size_t)BB * NN * 64);
}

// Round 6
// 2004.595 us; speedup vs baseline: 1.3131x; 1.0258x over previous
//
#include <hip/hip_runtime.h>

// Inputs: fp32. Outputs: fp32 (established round 3: PASSED).

constexpr int BB = 4;
constexpr int NN = 4096;
constexpr int M1 = 2048;
constexpr int M2 = 512;

// Exact fp32 squared distance matching numpy's (dx*dx) + (dy*dy), no fma contraction.
__device__ __forceinline__ float d2_exact(float dx, float dy) {
    return __fadd_rn(__fmul_rn(dx, dx), __fmul_rn(dy, dy));
}

// pick the slot with the larger (key_hi,key_lo) — keys unique (contain ~j).
__device__ __forceinline__ uint4 u4max(uint4 a, uint4 b) {
    unsigned long long ka = ((unsigned long long)a.x << 32) | (unsigned long long)a.y;
    unsigned long long kb = ((unsigned long long)b.x << 32) | (unsigned long long)b.y;
    return kb > ka ? b : a;
}

// One DPP combine stage: pull (key,payload) from CTRL-selected lanes, keep max.
// old = own value => lanes with invalid DPP source keep themselves (idempotent
// under max). v_mov_b32_dpp is VALU-speed vs ~30-50 cyc ds_permute shuffles
// (measured R3->R4 delta).
template<int CTRL>
__device__ __forceinline__ void dppc(unsigned& hi, unsigned& lo, float& x, float& y) {
    unsigned ohi = (unsigned)__builtin_amdgcn_update_dpp((int)hi, (int)hi, CTRL, 0xF, 0xF, false);
    unsigned olo = (unsigned)__builtin_amdgcn_update_dpp((int)lo, (int)lo, CTRL, 0xF, 0xF, false);
    float ox = __int_as_float(__builtin_amdgcn_update_dpp(__float_as_int(x), __float_as_int(x), CTRL, 0xF, 0xF, false));
    float oy = __int_as_float(__builtin_amdgcn_update_dpp(__float_as_int(y), __float_as_int(y), CTRL, 0xF, 0xF, false));
    unsigned long long ko = ((unsigned long long)ohi << 32) | (unsigned long long)olo;
    unsigned long long kk = ((unsigned long long)hi  << 32) | (unsigned long long)lo;
    bool t = ko > kk;
    hi = t ? ohi : hi;  lo = t ? olo : lo;
    x  = t ? ox  : x;   y  = t ? oy  : y;
}

// ---------------------------------------------------------------------------
// lf = tanh(tanh(x@W1+b1)@W2+b2) -> out (fp32); also
// y1[j,f] = lf_j@c1W[0:64] + zones_j*c1W[64] + pos_j@c1W[65:67] + c1b (fp32 ws)
// ---------------------------------------------------------------------------
__global__ __launch_bounds__(256) void k_lf_y1(
    const float2* __restrict__ x, const float* __restrict__ zones,
    const float* __restrict__ W1, const float* __restrict__ b1,
    const float* __restrict__ W2, const float* __restrict__ b2,
    const float* __restrict__ c1W, const float* __restrict__ c1b,
    float* __restrict__ out_lf, float* __restrict__ y1)
{
    __shared__ float sh[4][64];
    __shared__ float sl[4][64];
    int tid = threadIdx.x;
    int p = tid >> 6, f = tid & 63;
    size_t pt = (size_t)blockIdx.x * 4 + p;      // 0 .. BB*NN-1
    float2 xv = x[pt];
    float hid = tanhf(xv.x * W1[f] + xv.y * W1[64 + f] + b1[f]);
    sh[p][f] = hid;
    __syncthreads();
    float acc = b2[f];
#pragma unroll
    for (int c = 0; c < 64; ++c) acc += sh[p][c] * W2[c * 64 + f];
    float lf = tanhf(acc);
    sl[p][f] = lf;
    out_lf[pt * 64 + f] = lf;
    __syncthreads();
    float acc2 = c1b[f] + zones[pt] * c1W[64 * 64 + f]
               + xv.x * c1W[65 * 64 + f] + xv.y * c1W[66 * 64 + f];
#pragma unroll
    for (int c = 0; c < 64; ++c) acc2 += sl[p][c] * c1W[c * 64 + f];
    y1[pt * 64 + f] = acc2;
}

// ---------------------------------------------------------------------------
// Farthest point sampling — bit-exact vs reference scan:
//   min_d2 init 1e10; min vs last center; argmax with FIRST-index tie-break
//   (u64 key = bits(min_d2)<<32 | (0xFFFFFFFF - j); md>=0 so the f32 bit
//   pattern is value-monotone).
// KEY STRUCTURAL RULE: NO global-memory ops inside the loop. __syncthreads
// forces s_waitcnt vmcnt(0) before s_barrier, so any in-loop global store
// makes every iteration drain to L2/HBM (~900 cyc — the R3-R5 mystery cost).
// Centers accumulate in LDS; one cooperative copy-out at the end.
// 512 threads (8 waves), PPT=NP/512 (8 or 4 — no VGPR spill; R5's PPT=16
// spilled at VGPR=40). Wave reduce: 6 DPP stages carrying (key,x,y);
// parity-double-buffered slots => ONE barrier/iter; 8-slot tree after.
// ---------------------------------------------------------------------------
template<int NP, int M>
__global__ __launch_bounds__(512) void k_fps(const float2* __restrict__ pos,
                                             float* __restrict__ ctr)
{
    constexpr int PPT = NP / 512;
    __shared__ uint4 slots[2][8];
    __shared__ float2 cent[M];
    int b = blockIdx.x, tid = threadIdx.x;
    const float2* p = pos + (size_t)b * NP;

    float px[PPT], py[PPT], md[PPT];
#pragma unroll
    for (int q = 0; q < PPT; ++q) {
        float2 v = p[tid + q * 512];
        px[q] = v.x; py[q] = v.y;
        md[q] = 1e10f;
    }
    float2 c0 = p[0];
    float cx = c0.x, cy = c0.y;
    if (tid == 0) cent[0] = c0;

    for (int it = 1; it < M; ++it) {
        // per-lane min-update + argmax (branchless; q ascends with j so
        // strict > keeps the first index within the lane)
        float bm = -1.0f, bx = 0.0f, by = 0.0f;
        int bq = 0;
#pragma unroll
        for (int q = 0; q < PPT; ++q) {
            float dx = px[q] - cx, dy = py[q] - cy;
            float m = fminf(md[q], d2_exact(dx, dy));
            md[q] = m;
            bool g = m > bm;
            bm = g ? m : bm;
            bq = g ? q : bq;
            bx = g ? px[q] : bx;
            by = g ? py[q] : by;
        }
        unsigned hi = __float_as_uint(bm);
        unsigned lo = 0xFFFFFFFFu - (unsigned)(tid + (bq << 9));   // ~j, j=tid+q*512
        dppc<0x111>(hi, lo, bx, by);   // row_shr:1
        dppc<0x112>(hi, lo, bx, by);   // row_shr:2
        dppc<0x114>(hi, lo, bx, by);   // row_shr:4
        dppc<0x118>(hi, lo, bx, by);   // row_shr:8
        dppc<0x142>(hi, lo, bx, by);   // row_bcast:15
        dppc<0x143>(hi, lo, bx, by);   // row_bcast:31
        int par = it & 1;
        if ((tid & 63) == 63)
            slots[par][tid >> 6] = make_uint4(hi, lo, __float_as_uint(bx),
                                              __float_as_uint(by));
        __syncthreads();                 // drains only LDS ops (cheap)
        uint4 s0 = slots[par][0], s1 = slots[par][1];
        uint4 s2 = slots[par][2], s3 = slots[par][3];
        uint4 s4 = slots[par][4], s5 = slots[par][5];
        uint4 s6 = slots[par][6], s7 = slots[par][7];
        uint4 w = u4max(u4max(u4max(s0, s1), u4max(s2, s3)),
                        u4max(u4max(s4, s5), u4max(s6, s7)));
        cx = __uint_as_float(w.z);
        cy = __uint_as_float(w.w);
        if (tid == 0) cent[it] = make_float2(cx, cy);
    }
    __syncthreads();
    float2* co = (float2*)(ctr + (size_t)b * M * 2);
    for (int i = tid; i < M; i += 512) co[i] = cent[i];
}

// ---------------------------------------------------------------------------
// Set abstraction: h[i,f] = max_{j: d2(j,i)<=r2} y[j,f]  -  ctr_i @ W_rel.
// One block per center. Exact ball membership; max is order-free.
// ---------------------------------------------------------------------------
__global__ __launch_bounds__(256) void k_sa(
    const float2* __restrict__ candpos, const float* __restrict__ y,
    const float* __restrict__ ctr, const float* __restrict__ W,
    int NP, int F, int relrow, float r2, float* __restrict__ hout)
{
    __shared__ int cnt;
    __shared__ int list[4096];
    int tid = threadIdx.x;
    int b = blockIdx.y;
    size_t crow = (size_t)b * gridDim.x + blockIdx.x;
    if (tid == 0) cnt = 0;
    __syncthreads();
    float cx = ctr[crow * 2], cy = ctr[crow * 2 + 1];
    const float2* cp = candpos + (size_t)b * NP;
    for (int j = tid; j < NP; j += 256) {
        float2 pj = cp[j];
        float d2 = d2_exact(pj.x - cx, pj.y - cy);
        if (d2 <= r2) { int t = atomicAdd(&cnt, 1); list[t] = j; }
    }
    __syncthreads();
    int n = cnt;
    for (int f = tid; f < F; f += 256) {
        float m = -3.0e38f;
        for (int t = 0; t < n; ++t)
            m = fmaxf(m, y[((size_t)b * NP + list[t]) * F + f]);
        float ct = cx * W[(size_t)relrow * F + f] + cy * W[(size_t)(relrow + 1) * F + f];
        hout[crow * F + f] = m - ct;
    }
}

// ---------------------------------------------------------------------------
// y2[j,f] = h1_j @ c2W[0:64] + pos_j @ c2W[64:66] + c2b   (one block / point)
// ---------------------------------------------------------------------------
__global__ __launch_bounds__(128) void k_y2(
    const float* __restrict__ h1, const float* __restrict__ p1,
    const float* __restrict__ W, const float* __restrict__ bb,
    float* __restrict__ y2)
{
    __shared__ float sh[64];
    size_t row = blockIdx.x;
    int f = threadIdx.x;
    if (f < 64) sh[f] = h1[row * 64 + f];
    __syncthreads();
    float acc = bb[f] + p1[row * 2] * W[64 * 128 + f]
              + p1[row * 2 + 1] * W[65 * 128 + f];
#pragma unroll
    for (int c = 0; c < 64; ++c) acc += sh[c] * W[c * 128 + f];
    y2[row * 128 + f] = acc;
}

// ---------------------------------------------------------------------------
// g[i,f] = [h2_i, pos_i] @ c3W + c3b; partial max over 8 rows/thread.
// ---------------------------------------------------------------------------
__global__ __launch_bounds__(256) void k_g(
    const float* __restrict__ h2, const float* __restrict__ p2,
    const float* __restrict__ W3, const float* __restrict__ b3,
    float* __restrict__ part)
{
    int f = blockIdx.x * 256 + threadIdx.x;
    int b = blockIdx.z;
    int i0 = blockIdx.y * 8;
    float acc[8];
    float bbv = b3[f];
#pragma unroll
    for (int ii = 0; ii < 8; ++ii) acc[ii] = bbv;
    const float* hrow = h2 + ((size_t)b * M2 + i0) * 128;
    for (int c = 0; c < 128; ++c) {
        float w = W3[(size_t)c * 1024 + f];
#pragma unroll
        for (int ii = 0; ii < 8; ++ii) acc[ii] += hrow[ii * 128 + c] * w;
    }
    float wx = W3[(size_t)128 * 1024 + f];
    float wy = W3[(size_t)129 * 1024 + f];
    const float* prow = p2 + ((size_t)b * M2 + i0) * 2;
    float m = -3.0e38f;
#pragma unroll
    for (int ii = 0; ii < 8; ++ii) {
        float g = acc[ii] + prow[ii * 2] * wx + prow[ii * 2 + 1] * wy;
        m = fmaxf(m, g);
    }
    part[((size_t)b * 64 + blockIdx.y) * 1024 + f] = m;
}

__global__ __launch_bounds__(256) void k_gmax(const float* __restrict__ part,
                                              float* __restrict__ outg)
{
    int f = blockIdx.x * 256 + threadIdx.x;   // 0..4095
    int b = f >> 10, fl = f & 1023;
    float m = -3.0e38f;
#pragma unroll 8
    for (int ig = 0; ig < 64; ++ig)
        m = fmaxf(m, part[((size_t)b * 64 + ig) * 1024 + fl]);
    outg[f] = m;
}

extern "C" void kernel_launch(void* const* d_in, const int* in_sizes, int n_in,
                              void* d_out, int out_size, void* d_ws, size_t ws_size,
                              hipStream_t stream)
{
    const float* x    = (const float*)d_in[0];
    const float* zon  = (const float*)d_in[1];
    const float* lfW1 = (const float*)d_in[2];
    const float* lfb1 = (const float*)d_in[3];
    const float* lfW2 = (const float*)d_in[4];
    const float* lfb2 = (const float*)d_in[5];
    const float* c1W  = (const float*)d_in[6];
    const float* c1b  = (const float*)d_in[7];
    const float* c2W  = (const float*)d_in[8];
    const float* c2b  = (const float*)d_in[9];
    const float* c3W  = (const float*)d_in[10];
    const float* c3b  = (const float*)d_in[11];
    float* out = (float*)d_out;

    // Workspace (fp32). "big" (4 MB) reused: y1 -> y2 -> part.
    char* w = (char*)d_ws;
    float* big = (float*)w;                    w += (size_t)BB * NN * 64 * 4;   // 4 MB
    float* p1  = (float*)w;                    w += (size_t)BB * M1 * 2 * 4;
    float* h1  = (float*)w;                    w += (size_t)BB * M1 * 64 * 4;   // 2 MB
    float* p2  = (float*)w;                    w += (size_t)BB * M2 * 2 * 4;
    float* h2  = (float*)w;                    w += (size_t)BB * M2 * 128 * 4;  // 1 MB
    float* y1 = big, * y2 = big, * part = big;

    k_lf_y1<<<BB * NN / 4, 256, 0, stream>>>((const float2*)x, zon, lfW1, lfb1,
                                             lfW2, lfb2, c1W, c1b, out, y1);
    k_fps<NN, M1><<<BB, 512, 0, stream>>>((const float2*)x, p1);
    k_sa<<<dim3(M1, BB), 256, 0, stream>>>((const float2*)x, y1, p1, c1W,
                                           NN, 64, 65, 0.25f, h1);
    k_fps<M1, M2><<<BB, 512, 0, stream>>>((const float2*)p1, p2);
    k_y2<<<BB * M1, 128, 0, stream>>>(h1, p1, c2W, c2b, y2);
    k_sa<<<dim3(M2, BB), 256, 0, stream>>>((const float2*)p1, y2, p2, c2W,
                                           M1, 128, 64, 1.0f, h2);
    k_g<<<dim3(4, 64, BB), 256, 0, stream>>>(h2, p2, c3W, c3b, part);
    k_gmax<<<16, 256, 0, stream>>>(part, out + (size_t)BB * NN * 64);
}